// Round 11
// baseline (177.560 us; speedup 1.0000x reference)
//
#include <hip/hip_runtime.h>
#include <hip/hip_bf16.h>

#define C_DIM 256
#define W_DIM 4096
#define WI 30
#define NCH 137                    // ceil(4096/30)
#define TOTAL_CHUNKS (16*NCH)      // 2192
#define GRID 256
#define LDS_BYTES 89344

typedef unsigned short u16;
typedef short s16x8 __attribute__((ext_vector_type(8)));
typedef unsigned short u16x8 __attribute__((ext_vector_type(8)));
typedef unsigned short u16x4 __attribute__((ext_vector_type(4)));
typedef float f32x16 __attribute__((ext_vector_type(16)));

__device__ __forceinline__ u16 f2b(float f) {
  return __builtin_bit_cast(u16, __float2bfloat16(f));
}
__device__ __forceinline__ float b2f(u16 u) {
  return __builtin_bit_cast(float, ((unsigned)u) << 16);
}

// lgkm-only barrier: leaves vmem (DMA / stores / A-loads) in flight
__device__ __forceinline__ void bar_lgkm() {
  asm volatile("s_waitcnt lgkmcnt(0)" ::: "memory");
  __builtin_amdgcn_sched_barrier(0);
  __builtin_amdgcn_s_barrier();
  __builtin_amdgcn_sched_barrier(0);
}
__device__ __forceinline__ void bar_full() {
  asm volatile("s_waitcnt vmcnt(0) lgkmcnt(0)" ::: "memory");
  __builtin_amdgcn_sched_barrier(0);
  __builtin_amdgcn_s_barrier();
  __builtin_amdgcn_sched_barrier(0);
}

// ---------------- prep kernel (unchanged) ----------------
// ws: [0,131072) M bf16 [256][256]; [131072,262144) Wv bf16;
//     [262144) u0[256] f32; [263168) u1[256] f32; [264192) c0 f32
__global__ __launch_bounds__(256) void prep_kernel(
    const float* __restrict__ Wq, const float* __restrict__ bq,
    const float* __restrict__ Wk, const float* __restrict__ bk,
    const float* __restrict__ Wv, char* __restrict__ ws) {
  u16* Mb   = (u16*)ws;
  u16* Wvb  = (u16*)(ws + 131072);
  float* u0 = (float*)(ws + 262144);
  float* u1 = (float*)(ws + 263168);
  float* c0p = (float*)(ws + 264192);
  int bid = blockIdx.x, t = threadIdx.x;
  if (bid < 256) {
    __shared__ float Wqs[256*17];
    __shared__ float Wks[256*17];
    int i0 = (bid >> 4) << 4, j0 = (bid & 15) << 4;
    for (int it = 0; it < 16; ++it) {
      int e = t + 256*it; int a = e >> 4, ii = e & 15;
      Wqs[a*17+ii] = Wq[a*256 + i0 + ii];
      Wks[a*17+ii] = Wk[a*256 + j0 + ii];
    }
    __syncthreads();
    int ii = t >> 4, jj = t & 15;
    float acc = 0.f;
    #pragma unroll 8
    for (int a = 0; a < 256; ++a) acc += Wqs[a*17+ii] * Wks[a*17+jj];
    Mb[(i0+ii)*256 + j0 + jj] = f2b(acc);
  } else if (bid == 256) {
    int j = t;
    float a0 = 0.f, a1 = 0.f;
    #pragma unroll 4
    for (int a = 0; a < 256; ++a) {
      a0 += bq[a] * Wk[a*256 + j];
      a1 += bk[a] * Wq[a*256 + j];
    }
    u0[j] = a0; u1[j] = a1;
    __shared__ float red[256];
    red[t] = bq[t] * bk[t];
    __syncthreads();
    if (t == 0) { float s = 0.f; for (int a = 0; a < 256; ++a) s += red[a]; *c0p = s; }
  } else {
    int base = ((bid - 257)*256 + t) * 4;
    const float4 v = *reinterpret_cast<const float4*>(Wv + base);
    ushort4 pk = make_ushort4(f2b(v.x), f2b(v.y), f2b(v.z), f2b(v.w));
    *reinterpret_cast<ushort4*>(Wvb + base) = pk;
  }
}

// DMA one chunk's x-slice (256 rows x 32 cols f32, addr-clamped) into a Xf buffer.
// Wave wv stages rows 32wv..32wv+31 (wave-private: same wave converts them later).
__device__ __forceinline__ void stage_chunk(const float* xb, int w0, char* XfB,
                                            int wv, int l) {
  int col = l & 31, ro = l >> 5;
  int wcl = w0 - 1 + col;
  wcl = wcl < 0 ? 0 : (wcl > W_DIM-1 ? W_DIM-1 : wcl);
  const float* gbase = xb + wcl + (size_t)ro * W_DIM;
  #pragma unroll
  for (int n = 0; n < 16; ++n) {
    int r0 = wv*32 + n*2;
    const float* g = gbase + (size_t)r0 * W_DIM;
    char* lp = XfB + r0*128;
    __builtin_amdgcn_global_load_lds(
        (const __attribute__((address_space(1))) unsigned*)g,
        (__attribute__((address_space(3))) unsigned*)lp, 4, 0, 0);
  }
}

// ---------------- main fused kernel ----------------
// 256 persistent blocks (1/CU), ~8.5 chunks each, depth-2 DMA pipeline.
// LDS 89344 B:
//   Xf0 [256][32] f32   32768 @0        (DMA buffers, wave-private rows)
//   Xf1 [256][32] f32   32768 @32768
//   Xt  [32][32][8] bf16 16384 @65536
//   Ps  time-shared      4096 @81920   (PsA 2x[16][32] / PsB 3x[8][32])
//   ABs [2][32] f32        256 @86016
//   U   [2][256] f32      2048 @86272
//   bvs [256] f32         1024 @88320
__global__ __launch_bounds__(512, 4) void main_kernel(
    const float* __restrict__ x, const char* __restrict__ ws,
    const float* __restrict__ bv, float* __restrict__ out) {
  const u16* Mb   = (const u16*)ws;
  const u16* Wvb  = (const u16*)(ws + 131072);
  const float* u0g = (const float*)(ws + 262144);
  const float* u1g = (const float*)(ws + 263168);
  const float c0  = *(const float*)(ws + 264192);

  extern __shared__ char lds[];
  u16*   Xt  = (u16*)(lds + 65536);
  float* Ps  = (float*)(lds + 81920);
  float* ABs = (float*)(lds + 86016);
  float* U   = (float*)(lds + 86272);
  float* bvs = (float*)(lds + 88320);

  const int bid = blockIdx.x;
  const int t = threadIdx.x;
  const int wv = t >> 6, l = t & 63;
  const int col = l & 31, half = l >> 5;
  const int idx16 = 2*wv + half;

  // ---- prologue: stage U/bvs, first DMA into buf0 ----
  if (t < 256) { U[t] = u0g[t]; U[256+t] = u1g[t]; bvs[t] = bv[t]; }
  {
    int b = bid / NCH, cw = bid - b*NCH;
    stage_chunk(x + (size_t)b*(C_DIM*W_DIM), cw*WI, lds, wv, l);
  }
  bar_full();

  int cur = 0;
  for (int ci = bid; ci < TOTAL_CHUNKS; ci += GRID) {
    const int b  = ci / NCH;
    const int cw = ci - b*NCH;
    const int w0 = cw * WI;
    float* outb = out + (size_t)b * (C_DIM*W_DIM);
    const float* Xfc = (const float*)(cur ? (lds + 32768) : lds);
    char* Xfn = cur ? lds : (lds + 32768);

    // ---- CONVERT: Xf[cur](f32) -> Xt(bf16) + alpha/beta partials (wave-private Xf rows) ----
    {
      float pa = 0.f, pb_ = 0.f;
      #pragma unroll
      for (int g = 0; g < 2; ++g) {
        int kk = idx16*2 + g;
        const float* U0 = U + kk*8;
        const float* U1 = U + 256 + kk*8;
        union { u16 u[8]; u16x8 vv; } pk;
        #pragma unroll
        for (int e = 0; e < 8; ++e) {
          float v = Xfc[(kk*8+e)*32 + col];
          pk.u[e] = f2b(v);
          pa  += U0[e] * v;
          pb_ += U1[e] * v;
        }
        *reinterpret_cast<u16x8*>(Xt + (kk*32 + col)*8) = pk.vv;
      }
      Ps[idx16*32 + col] = pa;
      Ps[512 + idx16*32 + col] = pb_;
    }
    bar_lgkm();   // BAR1: Xt/PsA visible

    // ---- GEMM1: G = M @ X (A1 loads in-loop; no DMA younger yet -> clean waits) ----
    f32x16 acc;
    #pragma unroll
    for (int r = 0; r < 16; ++r) acc[r] = 0.f;
    {
      const u16* Arow = Mb + (32*wv + col)*256 + 8*half;
      #pragma unroll
      for (int kk = 0; kk < 16; ++kk) {
        s16x8 a = *reinterpret_cast<const s16x8*>(Arow + 16*kk);
        s16x8 b0 = *reinterpret_cast<const s16x8*>(Xt + ((2*kk + half)*32 + col)*8);
        acc = __builtin_amdgcn_mfma_f32_32x32x16_bf16(a, b0, acc, 0, 0, 0);
      }
    }
    if (t < 64) {   // alpha/beta reduce
      int which = t >> 5, jj = t & 31;
      float s = 0.f;
      #pragma unroll
      for (int g = 0; g < 16; ++g) s += Ps[which*512 + g*32 + jj];
      ABs[which*32 + jj] = s;
    }
    bar_lgkm();   // BAR1.5: ABs visible; Ps transitions PsA -> PsB

    // ---- issue next-chunk DMA into Xf[cur^1] (A1 already consumed; only
    //      GEMM2's A2-consume will force-drain it -- that drain IS the transfer) ----
    __builtin_amdgcn_sched_barrier(0);
    {
      int cin = ci + GRID;
      if (cin < TOTAL_CHUNKS) {
        int bn = cin / NCH, cwn = cin - bn*NCH;
        stage_chunk(x + (size_t)bn*(C_DIM*W_DIM), cwn*WI, Xfn, wv, l);
      }
    }
    __builtin_amdgcn_sched_barrier(0);

    // ---- P2: score partials from acc -> PsB ----
    {
      float s0 = 0.f, s1 = 0.f, s2 = 0.f;
      const int e0 = 4*half;
      int jm = (col > 0)  ? col-1 : 0;
      int jp = (col < 31) ? col+1 : 31;
      #pragma unroll
      for (int q = 0; q < 4; ++q) {
        const u16* base = Xt + (4*wv + q)*32*8 + e0;
        u16x4 xm = *reinterpret_cast<const u16x4*>(base + jm*8);
        u16x4 xc = *reinterpret_cast<const u16x4*>(base + col*8);
        u16x4 xp = *reinterpret_cast<const u16x4*>(base + jp*8);
        #pragma unroll
        for (int r4 = 0; r4 < 4; ++r4) {
          float g0 = acc[4*q + r4];
          s2 += g0 * b2f(xm[r4]);
          s1 += g0 * b2f(xc[r4]);
          s0 += g0 * b2f(xp[r4]);
        }
      }
      s0 += __shfl_xor(s0, 32);
      s1 += __shfl_xor(s1, 32);
      s2 += __shfl_xor(s2, 32);
      if (half == 0) {
        float* PBw = Ps + wv*32;
        if (col < 31) PBw[0*256 + col+1] = s0;
        PBw[1*256 + col] = s1;
        if (col >= 1)  PBw[2*256 + col-1] = s2;
      }
    }
    bar_lgkm();   // BAR2

    // ---- P3: softmax (output j=col+1, w=w0+col; valid col<=29) + in-place mix ----
    {
      int jr = (col <= 29) ? col+1 : 30;
      float d0 = 0.f, d1 = 0.f, d2 = 0.f;
      #pragma unroll
      for (int g = 0; g < 8; ++g) {
        d0 += Ps[0*256 + g*32 + jr];
        d1 += Ps[1*256 + g*32 + jr];
        d2 += Ps[2*256 + g*32 + jr];
      }
      float am = ABs[jr-1], ac = ABs[jr], ap = ABs[jr+1];
      float be = ABs[32 + jr];
      float sc0 = (d0 + am + be + c0) * 0.0625f;
      float sc1 = (d1 + ac + be + c0) * 0.0625f;
      float sc2 = (d2 + ap + be + c0) * 0.0625f;
      int w = w0 + col;
      bool v0 = (w >= 1), v2 = (w + 1 < W_DIM);
      const float NEG = -1e30f;
      float m = fmaxf(v0 ? sc0 : NEG, fmaxf(sc1, v2 ? sc2 : NEG));
      float e0v = v0 ? __expf(sc0 - m) : 0.f;
      float e1v = __expf(sc1 - m);
      float e2v = v2 ? __expf(sc2 - m) : 0.f;
      float inv = 1.f / (e0v + e1v + e2v);
      float a0 = e0v*inv, a1 = e1v*inv, a2 = e2v*inv;
      const bool wr = (col <= 29);
      #pragma unroll
      for (int g = 0; g < 2; ++g) {
        int kk = idx16*2 + g;
        u16* base = Xt + kk*32*8;
        u16x8 xm  = *reinterpret_cast<const u16x8*>(base + ((col<=29)?col:29)*8);
        u16x8 xc_ = *reinterpret_cast<const u16x8*>(base + jr*8);
        u16x8 xp  = *reinterpret_cast<const u16x8*>(base + (jr+1)*8);
        union { u16 u[8]; u16x8 vv; } pk;
        #pragma unroll
        for (int e = 0; e < 8; ++e)
          pk.u[e] = f2b(a0*b2f(xm[e]) + a1*b2f(xc_[e]) + a2*b2f(xp[e]));
        if (wr) *reinterpret_cast<u16x8*>(base + (col+1)*8) = pk.vv;
      }
    }
    bar_lgkm();   // BAR3: mixed Xt visible

    // ---- GEMM2: out = Wv @ Xmix + bv (A2 consume drains the DMA) ----
    {
      #pragma unroll
      for (int r = 0; r < 16; ++r) acc[r] = 0.f;
      const u16* Arow2 = Wvb + (32*wv + col)*256 + 8*half;
      int jB = (col < 31) ? col+1 : 31;
      #pragma unroll
      for (int kk = 0; kk < 16; ++kk) {
        s16x8 a = *reinterpret_cast<const s16x8*>(Arow2 + 16*kk);
        s16x8 b0 = *reinterpret_cast<const s16x8*>(Xt + ((2*kk + half)*32 + jB)*8);
        acc = __builtin_amdgcn_mfma_f32_32x32x16_bf16(a, b0, acc, 0, 0, 0);
      }
      float bvr[16];
      #pragma unroll
      for (int q = 0; q < 4; ++q) {
        const float4 t4 = *reinterpret_cast<const float4*>(bvs + 32*wv + 8*q + 4*half);
        bvr[4*q+0] = t4.x; bvr[4*q+1] = t4.y; bvr[4*q+2] = t4.z; bvr[4*q+3] = t4.w;
      }
      int wgo = w0 + col;
      bool st = (col <= 29) && (wgo < W_DIM);
      #pragma unroll
      for (int r = 0; r < 16; ++r) {
        int crow = 32*wv + (r&3) + 8*(r>>2) + 4*half;
        if (st) outb[(size_t)crow*W_DIM + wgo] = acc[r] + bvr[r];
      }
    }
    bar_lgkm();   // BAR4: all waves' Xt/Ps reads done before next CONVERT overwrites
    cur ^= 1;
  }
}

extern "C" void kernel_launch(void* const* d_in, const int* in_sizes, int n_in,
                              void* d_out, int out_size, void* d_ws, size_t ws_size,
                              hipStream_t stream) {
  (void)in_sizes; (void)n_in; (void)out_size; (void)ws_size;
  const float* x  = (const float*)d_in[0];
  const float* Wq = (const float*)d_in[1];
  const float* bq = (const float*)d_in[2];
  const float* Wk = (const float*)d_in[3];
  const float* bk = (const float*)d_in[4];
  const float* Wv = (const float*)d_in[5];
  const float* bv = (const float*)d_in[6];
  float* out = (float*)d_out;
  char* ws = (char*)d_ws;   // needs 264196 B

  hipFuncSetAttribute((const void*)main_kernel,
                      hipFuncAttributeMaxDynamicSharedMemorySize, LDS_BYTES);
  prep_kernel<<<321, 256, 0, stream>>>(Wq, bq, Wk, bk, Wv, ws);
  main_kernel<<<GRID, 512, LDS_BYTES, stream>>>(x, ws, bv, out);
}

// Round 12
// 78.336 us; speedup vs baseline: 2.2666x; 2.2666x over previous
//
#include <hip/hip_runtime.h>
#include <hip/hip_bf16.h>

#define C_DIM 256
#define W_DIM 4096
#define LDS_BYTES 162512

typedef unsigned short u16;
typedef short s16x8 __attribute__((ext_vector_type(8)));
typedef unsigned short u16x8 __attribute__((ext_vector_type(8)));
typedef unsigned short u16x4 __attribute__((ext_vector_type(4)));
typedef float f32x16 __attribute__((ext_vector_type(16)));

__device__ __forceinline__ u16 f2b(float f) {
  return __builtin_bit_cast(u16, __float2bfloat16(f));
}
__device__ __forceinline__ float b2f(u16 u) {
  return __builtin_bit_cast(float, ((unsigned)u) << 16);
}

// ---------------- prep kernel (unchanged) ----------------
// ws: [0,131072) M bf16 [256][256]; [131072,262144) Wv bf16;
//     [262144) u0[256] f32; [263168) u1[256] f32; [264192) c0 f32
__global__ __launch_bounds__(256) void prep_kernel(
    const float* __restrict__ Wq, const float* __restrict__ bq,
    const float* __restrict__ Wk, const float* __restrict__ bk,
    const float* __restrict__ Wv, char* __restrict__ ws) {
  u16* Mb   = (u16*)ws;
  u16* Wvb  = (u16*)(ws + 131072);
  float* u0 = (float*)(ws + 262144);
  float* u1 = (float*)(ws + 263168);
  float* c0p = (float*)(ws + 264192);
  int bid = blockIdx.x, t = threadIdx.x;
  if (bid < 256) {
    __shared__ float Wqs[256*17];
    __shared__ float Wks[256*17];
    int i0 = (bid >> 4) << 4, j0 = (bid & 15) << 4;
    for (int it = 0; it < 16; ++it) {
      int e = t + 256*it; int a = e >> 4, ii = e & 15;
      Wqs[a*17+ii] = Wq[a*256 + i0 + ii];
      Wks[a*17+ii] = Wk[a*256 + j0 + ii];
    }
    __syncthreads();
    int ii = t >> 4, jj = t & 15;
    float acc = 0.f;
    #pragma unroll 8
    for (int a = 0; a < 256; ++a) acc += Wqs[a*17+ii] * Wks[a*17+jj];
    Mb[(i0+ii)*256 + j0 + jj] = f2b(acc);
  } else if (bid == 256) {
    int j = t;
    float a0 = 0.f, a1 = 0.f;
    #pragma unroll 4
    for (int a = 0; a < 256; ++a) {
      a0 += bq[a] * Wk[a*256 + j];
      a1 += bk[a] * Wq[a*256 + j];
    }
    u0[j] = a0; u1[j] = a1;
    __shared__ float red[256];
    red[t] = bq[t] * bk[t];
    __syncthreads();
    if (t == 0) { float s = 0.f; for (int a = 0; a < 256; ++a) s += red[a]; *c0p = s; }
  } else {
    int base = ((bid - 257)*256 + t) * 4;
    const float4 v = *reinterpret_cast<const float4*>(Wv + base);
    ushort4 pk = make_ushort4(f2b(v.x), f2b(v.y), f2b(v.z), f2b(v.w));
    *reinterpret_cast<ushort4*>(Wvb + base) = pk;
  }
}

// ---------------- main fused kernel ----------------
// 256 blocks = (b 0..15) x (tile 0..15 of 256 out cols). 512 thr, 1 block/CU.
// j = 0..257 <-> w = w0-1+j; out col oc = 0..255 <-> w = w0+oc (j' = oc+1).
// LDS 162512 B:
//   Xt  [kk 0..31][j 0..258][e 0..7] bf16   132608 @0     (col 258 = zero pad)
//   Ps  [3][8][258] f32 (PsA 2x overlays)    24768 @132608
//   ABs [2][258] f32                          2064 @157376
//   U   [2][256] f32                          2048 @159440
//   bvs [256] f32                             1024 @161488
__global__ __launch_bounds__(512, 2) void main_kernel(
    const float* __restrict__ x, const char* __restrict__ ws,
    const float* __restrict__ bv, float* __restrict__ out) {
  const u16* Mb   = (const u16*)ws;
  const u16* Wvb  = (const u16*)(ws + 131072);
  const float* u0g = (const float*)(ws + 262144);
  const float* u1g = (const float*)(ws + 263168);
  const float c0  = *(const float*)(ws + 264192);

  extern __shared__ char lds[];
  u16*   Xt  = (u16*)lds;
  float* Ps  = (float*)(lds + 132608);
  float* ABs = (float*)(lds + 157376);
  float* U   = (float*)(lds + 159440);
  float* bvs = (float*)(lds + 161488);

  const int bid = blockIdx.x;
  const int t = threadIdx.x;
  const int wv = t >> 6, l = t & 63;
  const int col = l & 31, half = l >> 5;

  const int b  = bid >> 4;
  const int cw = bid & 15;
  const int w0 = cw << 8;
  const float* xb = x + (size_t)b * (C_DIM*W_DIM);
  float* outb = out + (size_t)b * (C_DIM*W_DIM);

  if (t < 256) { U[t] = u0g[t]; U[256+t] = u1g[t]; bvs[t] = bv[t]; }
  __syncthreads();

  // ---- P0: stage x -> Xt bf16 (wave-private kk strips) + alpha/beta partials ----
  {
    #pragma unroll
    for (int p = 0; p < 4; ++p) {
      int j = 64*p + l;
      int w = w0 - 1 + j;                 // w <= w0+254 always in range
      bool ok = (w >= 0);
      const float* xp = xb + w;
      float xr[32];
      #pragma unroll
      for (int g = 0; g < 4; ++g)
        #pragma unroll
        for (int e = 0; e < 8; ++e)
          xr[g*8+e] = ok ? xp[(size_t)((4*wv+g)*8 + e) * W_DIM] : 0.f;
      float pa = 0.f, pb_ = 0.f;
      #pragma unroll
      for (int g = 0; g < 4; ++g) {
        int kk = 4*wv + g;
        union { u16 u[8]; u16x8 v; } pk;
        #pragma unroll
        for (int e = 0; e < 8; ++e) {
          float v = xr[g*8+e];
          pk.u[e] = f2b(v);
          pa  += U[kk*8+e] * v;
          pb_ += U[256 + kk*8+e] * v;
        }
        *reinterpret_cast<u16x8*>(Xt + (kk*259 + j)*8) = pk.v;
      }
      Ps[wv*258 + j] = pa;
      Ps[2064 + wv*258 + j] = pb_;
    }
    if (l < 3) {                           // j = 256,257 real; 258 zero pad
      int j = 256 + l;
      int w = w0 - 1 + j;
      bool real = (l < 2) && (w < W_DIM);
      const float* xpe = xb + w;
      float pa = 0.f, pb_ = 0.f;
      #pragma unroll
      for (int g = 0; g < 4; ++g) {
        int kk = 4*wv + g;
        union { u16 u[8]; u16x8 v; } pk;
        #pragma unroll
        for (int e = 0; e < 8; ++e) {
          float v = real ? xpe[(size_t)(kk*8+e) * W_DIM] : 0.f;
          pk.u[e] = f2b(v);
          pa  += U[kk*8+e] * v;
          pb_ += U[256 + kk*8+e] * v;
        }
        *reinterpret_cast<u16x8*>(Xt + (kk*259 + j)*8) = pk.v;
      }
      if (l < 2) {
        Ps[wv*258 + j] = pa;
        Ps[2064 + wv*258 + j] = pb_;
      }
    }
  }
  __syncthreads();   // bar1

  // ---- GEMM1: G = M @ X, 9 n-tiles (j = 32n+col; tile 8: j=256+col clamp->pad) ----
  f32x16 acc[9];
  #pragma unroll
  for (int n = 0; n < 9; ++n)
    #pragma unroll
    for (int r = 0; r < 16; ++r) acc[n][r] = 0.f;
  {
    int j8 = 256 + col; if (j8 > 258) j8 = 258;
    const u16* Arow = Mb + (32*wv + col)*256 + 8*half;
    #pragma unroll
    for (int kk = 0; kk < 16; ++kk) {
      s16x8 a = *reinterpret_cast<const s16x8*>(Arow + 16*kk);
      const u16* Bb = Xt + (2*kk + half)*259*8;
      #pragma unroll
      for (int n = 0; n < 8; ++n) {
        s16x8 bfr = *reinterpret_cast<const s16x8*>(Bb + (32*n + col)*8);
        acc[n] = __builtin_amdgcn_mfma_f32_32x32x16_bf16(a, bfr, acc[n], 0, 0, 0);
      }
      s16x8 bfr8 = *reinterpret_cast<const s16x8*>(Bb + j8*8);
      acc[8] = __builtin_amdgcn_mfma_f32_32x32x16_bf16(a, bfr8, acc[8], 0, 0, 0);
    }
  }
  // alpha/beta reduce (PsA consumed here)
  for (int i = t; i < 516; i += 512) {
    int which = (i >= 258) ? 1 : 0;
    int jj = i - 258*which;
    float s = 0.f;
    #pragma unroll
    for (int g = 0; g < 8; ++g) s += Ps[which*2064 + g*258 + jj];
    ABs[which*258 + jj] = s;
  }
  __syncthreads();   // bar2: Ps transitions PsA -> PsB

  // ---- P2: score partials from acc -> PsB ----
  // g col jt feeds: s1 -> D0(jt), s0 -> D-1(jt+1), s2 -> D+1(jt-1)
  {
    #pragma unroll
    for (int n = 0; n < 9; ++n) {
      int jt = (n < 8) ? (32*n + col) : (256 + col);
      int jm = jt - 1; if (jm < 0) jm = 0; if (jm > 258) jm = 258;
      int jc = (jt > 258) ? 258 : jt;
      int jp_ = jt + 1; if (jp_ > 258) jp_ = 258;
      float s0 = 0.f, s1 = 0.f, s2 = 0.f;
      #pragma unroll
      for (int q = 0; q < 4; ++q) {
        const u16* base = Xt + (4*wv + q)*259*8 + 4*half;
        u16x4 xm = *reinterpret_cast<const u16x4*>(base + jm*8);
        u16x4 xc = *reinterpret_cast<const u16x4*>(base + jc*8);
        u16x4 xp = *reinterpret_cast<const u16x4*>(base + jp_*8);
        #pragma unroll
        for (int r4 = 0; r4 < 4; ++r4) {
          float g0 = acc[n][4*q + r4];
          s2 += g0 * b2f(xm[r4]);
          s1 += g0 * b2f(xc[r4]);
          s0 += g0 * b2f(xp[r4]);
        }
      }
      s0 += __shfl_xor(s0, 32);
      s1 += __shfl_xor(s1, 32);
      s2 += __shfl_xor(s2, 32);
      if (half == 0) {
        if (jt <= 255)             Ps[0*2064 + wv*258 + jt+1] = s0;
        if (jt >= 1 && jt <= 256)  Ps[1*2064 + wv*258 + jt]   = s1;
        if (jt >= 2 && jt <= 257)  Ps[2*2064 + wv*258 + jt-1] = s2;
      }
    }
  }
  __syncthreads();   // bar3

  // ---- softmax (per lane: oc = 64p+l) + in-place mix of own kk strips ----
  {
    float aw0[4], aw1[4], aw2[4];
    #pragma unroll
    for (int p = 0; p < 4; ++p) {
      int oc = 64*p + l;
      int jp = oc + 1;
      float d0 = 0.f, d1 = 0.f, d2 = 0.f;
      #pragma unroll
      for (int g = 0; g < 8; ++g) {
        d0 += Ps[0*2064 + g*258 + jp];
        d1 += Ps[1*2064 + g*258 + jp];
        d2 += Ps[2*2064 + g*258 + jp];
      }
      float am = ABs[jp-1], ac_ = ABs[jp], ap_ = ABs[jp+1];
      float be = ABs[258 + jp];
      float sc0 = (d0 + am + be + c0) * 0.0625f;
      float sc1 = (d1 + ac_ + be + c0) * 0.0625f;
      float sc2 = (d2 + ap_ + be + c0) * 0.0625f;
      int w = w0 + oc;
      bool v0 = (w >= 1), v2 = (w + 1 < W_DIM);
      const float NEG = -1e30f;
      float m = fmaxf(v0 ? sc0 : NEG, fmaxf(sc1, v2 ? sc2 : NEG));
      float e0v = v0 ? __expf(sc0 - m) : 0.f;
      float e1v = __expf(sc1 - m);
      float e2v = v2 ? __expf(sc2 - m) : 0.f;
      float inv = 1.f / (e0v + e1v + e2v);
      aw0[p] = e0v*inv; aw1[p] = e1v*inv; aw2[p] = e2v*inv;
    }
    // mix: out col oc uses x at j = oc, oc+1, oc+2; write at j' = oc+1.
    // All 12 reads issued before any write (in-order LDS within wave).
    #pragma unroll
    for (int g = 0; g < 4; ++g) {
      u16* base = Xt + (4*wv + g)*259*8;
      u16x8 xrd[12];
      #pragma unroll
      for (int p = 0; p < 4; ++p)
        #pragma unroll
        for (int i = 0; i < 3; ++i)
          xrd[p*3+i] = *reinterpret_cast<const u16x8*>(base + (64*p + l + i)*8);
      __builtin_amdgcn_sched_barrier(0);
      #pragma unroll
      for (int p = 0; p < 4; ++p) {
        union { u16 u[8]; u16x8 v; } pk;
        #pragma unroll
        for (int e = 0; e < 8; ++e)
          pk.u[e] = f2b(aw0[p]*b2f(xrd[p*3][e]) + aw1[p]*b2f(xrd[p*3+1][e])
                        + aw2[p]*b2f(xrd[p*3+2][e]));
        *reinterpret_cast<u16x8*>(base + (64*p + l + 1)*8) = pk.v;
      }
      __builtin_amdgcn_sched_barrier(0);
    }
  }
  __syncthreads();   // bar4

  // ---- GEMM2: out = Wv @ Xmix + bv, 8 n-tiles, dense aligned stores ----
  {
    f32x16 acc2[8];
    #pragma unroll
    for (int n = 0; n < 8; ++n)
      #pragma unroll
      for (int r = 0; r < 16; ++r) acc2[n][r] = 0.f;
    const u16* Arow2 = Wvb + (32*wv + col)*256 + 8*half;
    #pragma unroll
    for (int kk = 0; kk < 16; ++kk) {
      s16x8 a = *reinterpret_cast<const s16x8*>(Arow2 + 16*kk);
      const u16* Bb = Xt + (2*kk + half)*259*8;
      #pragma unroll
      for (int n = 0; n < 8; ++n) {
        s16x8 bfr = *reinterpret_cast<const s16x8*>(Bb + (1 + 32*n + col)*8);
        acc2[n] = __builtin_amdgcn_mfma_f32_32x32x16_bf16(a, bfr, acc2[n], 0, 0, 0);
      }
    }
    float bvr[16];
    #pragma unroll
    for (int q = 0; q < 4; ++q) {
      const float4 t4 = *reinterpret_cast<const float4*>(bvs + 32*wv + 8*q + 4*half);
      bvr[4*q+0] = t4.x; bvr[4*q+1] = t4.y; bvr[4*q+2] = t4.z; bvr[4*q+3] = t4.w;
    }
    #pragma unroll
    for (int n = 0; n < 8; ++n)
      #pragma unroll
      for (int r = 0; r < 16; ++r) {
        int crow = 32*wv + (r&3) + 8*(r>>2) + 4*half;
        outb[(size_t)crow*W_DIM + w0 + 32*n + col] = acc2[n][r] + bvr[r];
      }
  }
}

extern "C" void kernel_launch(void* const* d_in, const int* in_sizes, int n_in,
                              void* d_out, int out_size, void* d_ws, size_t ws_size,
                              hipStream_t stream) {
  (void)in_sizes; (void)n_in; (void)out_size; (void)ws_size;
  const float* x  = (const float*)d_in[0];
  const float* Wq = (const float*)d_in[1];
  const float* bq = (const float*)d_in[2];
  const float* Wk = (const float*)d_in[3];
  const float* bk = (const float*)d_in[4];
  const float* Wv = (const float*)d_in[5];
  const float* bv = (const float*)d_in[6];
  float* out = (float*)d_out;
  char* ws = (char*)d_ws;   // needs 264196 B

  hipFuncSetAttribute((const void*)main_kernel,
                      hipFuncAttributeMaxDynamicSharedMemorySize, LDS_BYTES);
  prep_kernel<<<321, 256, 0, stream>>>(Wq, bq, Wk, bk, Wv, ws);
  main_kernel<<<256, 512, LDS_BYTES, stream>>>(x, ws, bv, out);
}